// Round 10
// baseline (461.174 us; speedup 1.0000x reference)
//
#include <hip/hip_runtime.h>

typedef unsigned short u16;
typedef unsigned int u32;
typedef __attribute__((ext_vector_type(8))) short bf16x8;   // 8 bf16 = 4 VGPRs
typedef __attribute__((ext_vector_type(4))) float f32x4;
typedef __attribute__((ext_vector_type(2))) unsigned int u32x2;

#define NBATCH 4
#define DDIM   128
#define NHEAD  8
#define PTOT   12544
#define CWID   112     // patch grid width
#define NTOK   49      // tokens per 7x7 window
#define PSTR   68      // p_lds row stride (u16 elems)

// LDS region offsets (u16 units). xw overlays qs/ks (consumed into regs first).
#define OFF_QS 0                    // 49*128 = 6272  q^T [t][d]
#define OFF_KS 6272                 // 49*128 = 6272  k^T [t][d]
#define OFF_US 12544                // 128*64 = 8192  U^T [dd][i]
#define OFF_PL 20736                // 49*68  = 3332  P^T [j][i]
#define OFF_PC 24068                // 169*8  = 1352  pos bias bf16
#define LDS_TOT 25420               // 50840 B -> 3 blocks/CU target

// ws layout (u16 units): Wq16 | Wk16 | Wc16 (8 x 128x128) | bcv fp32 (1024 f)
#define WS_WK  131072
#define WS_WC  262144
#define WS_BCV 393216

__device__ __forceinline__ int swz128(int row, int col) {
    return row * 128 + ((((col >> 3) ^ row) & 15) << 3) + (col & 7);
}
__device__ __forceinline__ float bf2f(u16 u) {
    union { u32 i; float f; } x; x.i = ((u32)u) << 16; return x.f;
}
__device__ __forceinline__ u16 f2bf(float f) {
    union { float f; u32 u; } v; v.f = f;
    return (u16)((v.u + 0x7fffu + ((v.u >> 16) & 1u)) >> 16);
}

// ---- single prepass: blocks 0..7 build Wc_h/bcv_h via MFMA; blocks 8..263 cvt Wq,Wk ----
__global__ void __launch_bounds__(256) prep(
    const float* __restrict__ Wq, const float* __restrict__ Wk,
    const float* __restrict__ Wv, const float* __restrict__ Wo,
    const float* __restrict__ bv, u16* __restrict__ ws)
{
    const int tid = threadIdx.x;
    const int b = blockIdx.x;
    if (b >= 8) {                       // convert Wq|Wk fp32 -> bf16
        const int base = (b - 8) * 1024;
        for (int i = tid; i < 1024; i += 256) {
            const int t = base + i;
            ws[t] = f2bf(t < 131072 ? Wq[t] : Wk[t - 131072]);
        }
        return;
    }
    // head GEMM: Wc_h[dd][d] = sum_dh Wo_h[dd][dh] * Wv_h[dh][d]
    __shared__ u16 lm[32768];           // [0): Wo_h [dd][dh]; [16384): Wv_h^T [d][dh]
    const int h = b;
    for (int idx = tid; idx < 16384; idx += 256) {
        const int dd = idx >> 7, dh = idx & 127;
        lm[swz128(dd, dh)] = f2bf(Wo[dd * 1024 + h * 128 + dh]);
    }
    for (int idx = tid; idx < 16384; idx += 256) {
        const int dh = idx >> 7, d = idx & 127;
        lm[16384 + swz128(d, dh)] = f2bf(Wv[(h * 128 + dh) * 128 + d]);
    }
    // bcv (global reads, fp32)
    if (tid < 128) {
        float s = 0.f;
        for (int dh = 0; dh < 128; ++dh)
            s += Wo[tid * 1024 + h * 128 + dh] * bv[h * 128 + dh];
        ((float*)(ws + WS_BCV))[h * 128 + tid] = s;
    }
    __syncthreads();
    const int w = tid >> 6, lane = tid & 63, quad = lane >> 4, lid = lane & 15;
    const f32x4 z4 = {0.f, 0.f, 0.f, 0.f};
    u16* wcg = ws + WS_WC + h * 16384;
    #pragma unroll
    for (int mtl = 0; mtl < 2; ++mtl) {
        const int mt = 2 * w + mtl;
        bf16x8 A[4];
        #pragma unroll
        for (int kt = 0; kt < 4; ++kt)
            A[kt] = *(const bf16x8*)(lm + swz128(mt * 16 + lid, kt * 32 + quad * 8));
        #pragma unroll
        for (int nt = 0; nt < 8; ++nt) {
            f32x4 acc = z4;
            #pragma unroll
            for (int kt = 0; kt < 4; ++kt) {
                bf16x8 B = *(const bf16x8*)(lm + 16384 + swz128(nt * 16 + lid, kt * 32 + quad * 8));
                acc = __builtin_amdgcn_mfma_f32_16x16x32_bf16(A[kt], B, acc, 0, 0, 0);
            }
            #pragma unroll
            for (int r = 0; r < 4; ++r)
                wcg[(mt * 16 + quad * 4 + r) * 128 + nt * 16 + lid] = f2bf(acc[r]);
        }
    }
}

// 256 threads = 4 waves; wave w owns query group j in [16w,16w+16).
// x-window fragments held in 64 VGPRs for the whole kernel (A-frag == B-frag layout).
__global__ void __launch_bounds__(256, 3)
winattn(const float* __restrict__ xg, const u16* __restrict__ ws,
        const float* __restrict__ bq, const float* __restrict__ bk,
        const float* __restrict__ bo, const float* __restrict__ posf,
        float* __restrict__ out)
{
    __shared__ u16 sm[LDS_TOT];
    u16* xw = sm;            // x window [t][d] — overlays qs/ks, dead after frag load
    u16* qs = sm + OFF_QS;
    u16* ks = sm + OFF_KS;
    u16* us = sm + OFF_US;   // U^T [dd][i]
    u16* pl = sm + OFF_PL;   // P^T [j][i], wave-private rows
    u16* pc = sm + OFF_PC;   // pos bias [169][8] bf16

    const int tid  = threadIdx.x;
    const int w    = tid >> 6;
    const int lane = tid & 63;
    const int quad = lane >> 4;
    const int lid  = lane & 15;
    const int bx   = blockIdx.x;
    const int n    = bx >> 8;
    const int win  = bx & 255;
    const int pbase = (win >> 4) * 7 * CWID + (win & 15) * 7;

    const bf16x8 zf = {0,0,0,0,0,0,0,0};
    const f32x4  z4 = {0.f,0.f,0.f,0.f};

    const u16* Wqw = ws;
    const u16* Wkw = ws + WS_WK;
    const u16* Wcw = ws + WS_WC;
    const float* bcv = (const float*)(ws + WS_BCV);

    // ---- stage pos table + x window ----
    for (int i = tid; i < 169 * NHEAD; i += 256) pc[i] = f2bf(posf[i]);
    const float* xn = xg + n * DDIM * PTOT;
    for (int idx = tid; idx < DDIM * NTOK; idx += 256) {
        int d = idx / NTOK;
        int t = idx - d * NTOK;
        int a = t / 7, b = t - a * 7;
        xw[swz128(t, d)] = f2bf(xn[d * PTOT + pbase + a * CWID + b]);
    }
    __syncthreads();

    // ---- hoist x fragments to registers (shared by q/k A-operand and U B-operand) ----
    bf16x8 xfrag[4][4];
    #pragma unroll
    for (int mt = 0; mt < 4; ++mt)
        #pragma unroll
        for (int kt = 0; kt < 4; ++kt)
            xfrag[mt][kt] = (mt * 16 + lid < NTOK)
                ? *(const bf16x8*)(xw + swz128(mt * 16 + lid, kt * 32 + quad * 8)) : zf;
    __syncthreads();   // xw reads done -> qs/ks may overlay

    f32x4 outacc[8];
    #pragma unroll
    for (int nt = 0; nt < 8; ++nt) outacc[nt] = z4;

    const int j = 16 * w + lid;
    const int jc = j < NTOK ? j : NTOK - 1;

    for (int h = 0; h < NHEAD; ++h) {
        // ======== stage A: q,k projections + U = x*Wc^T + bcv ========
        for (int sel = 0; sel < 2; ++sel) {
            const u16* W    = sel ? Wkw : Wqw;
            const float* bb = sel ? bk : bq;
            u16* dst        = sel ? ks : qs;
            #pragma unroll
            for (int ntl = 0; ntl < 2; ++ntl) {
                const int nt = 2 * w + ntl;
                const int drow = h * 128 + nt * 16 + lid;
                bf16x8 B[4];
                #pragma unroll
                for (int kt = 0; kt < 4; ++kt)
                    B[kt] = *(const bf16x8*)(W + drow * 128 + kt * 32 + quad * 8);
                const float bias = bb[drow];
                #pragma unroll
                for (int mt = 0; mt < 4; ++mt) {
                    f32x4 acc = z4;
                    #pragma unroll
                    for (int kt = 0; kt < 4; ++kt)
                        acc = __builtin_amdgcn_mfma_f32_16x16x32_bf16(xfrag[mt][kt], B[kt], acc, 0, 0, 0);
                    #pragma unroll
                    for (int r = 0; r < 4; ++r) {
                        const int t = mt * 16 + quad * 4 + r;
                        if (t < NTOK)
                            dst[swz128(t, nt * 16 + lid)] = f2bf(acc[r] + bias);
                    }
                }
            }
        }
        // U^T[dd][i]
        #pragma unroll
        for (int mtl = 0; mtl < 2; ++mtl) {
            const int mt = 2 * w + mtl;
            bf16x8 A[4];
            #pragma unroll
            for (int kt = 0; kt < 4; ++kt)
                A[kt] = *(const bf16x8*)(Wcw + h * 16384 + (mt * 16 + lid) * 128 + kt * 32 + quad * 8);
            float bias[4];
            #pragma unroll
            for (int r = 0; r < 4; ++r)
                bias[r] = bcv[h * 128 + mt * 16 + quad * 4 + r];
            #pragma unroll
            for (int nt = 0; nt < 4; ++nt) {
                f32x4 acc = z4;
                #pragma unroll
                for (int kt = 0; kt < 4; ++kt)
                    acc = __builtin_amdgcn_mfma_f32_16x16x32_bf16(A[kt], xfrag[nt][kt], acc, 0, 0, 0);
                #pragma unroll
                for (int r = 0; r < 4; ++r)
                    us[(mt * 16 + quad * 4 + r) * 64 + ((((nt * 16 + lid) >> 3) ^ (mt * 16 + quad * 4 + r)) & 7) * 8 + ((nt * 16 + lid) & 7)] = f2bf(acc[r] + bias[r]);
            }
        }
        __syncthreads();

        // ======== stage B: S = k^T q, softmax, P write (wave-local) ========
        bf16x8 Bq[4];
        #pragma unroll
        for (int kt = 0; kt < 4; ++kt) {
            Bq[kt] = zf;
            if (j < NTOK)
                Bq[kt] = *(const bf16x8*)(qs + swz128(j, kt * 32 + quad * 8));
        }
        f32x4 S[4];
        #pragma unroll
        for (int mt = 0; mt < 4; ++mt) {
            S[mt] = z4;
            #pragma unroll
            for (int kt = 0; kt < 4; ++kt) {
                bf16x8 A = *(const bf16x8*)(ks + swz128(mt * 16 + lid, kt * 32 + quad * 8));
                S[mt] = __builtin_amdgcn_mfma_f32_16x16x32_bf16(A, Bq[kt], S[mt], 0, 0, 0);
            }
        }
        const int aj = jc / 7, bj = jc - aj * 7;
        float sv[4][4];
        float mx = -3.0e38f;
        #pragma unroll
        for (int mt = 0; mt < 4; ++mt)
            #pragma unroll
            for (int r = 0; r < 4; ++r) {
                const int ii = mt * 16 + quad * 4 + r;
                float vvv;
                if (ii < NTOK) {
                    const int ai = ii / 7, bi = ii - ai * 7;
                    const int rel = (ai - aj + 6) + 13 * (bi - bj + 6);
                    vvv = S[mt][r] * 0.08838834764831845f + bf2f(pc[rel * NHEAD + h]);
                } else {
                    vvv = -3.0e38f;
                }
                sv[mt][r] = vvv;
                mx = fmaxf(mx, vvv);
            }
        mx = fmaxf(mx, __shfl_xor(mx, 16));
        mx = fmaxf(mx, __shfl_xor(mx, 32));
        float ssum = 0.f;
        #pragma unroll
        for (int mt = 0; mt < 4; ++mt)
            #pragma unroll
            for (int r = 0; r < 4; ++r) {
                const float e = __expf(sv[mt][r] - mx);
                sv[mt][r] = e;
                ssum += e;
            }
        ssum += __shfl_xor(ssum, 16);
        ssum += __shfl_xor(ssum, 32);
        const float inv = 1.0f / ssum;
        if (j < NTOK) {
            #pragma unroll
            for (int mt = 0; mt < 4; ++mt) {
                union { u16 s[4]; u32x2 u; } pk;
                #pragma unroll
                for (int r = 0; r < 4; ++r) pk.s[r] = f2bf(sv[mt][r] * inv);
                *(u32x2*)(pl + j * PSTR + mt * 16 + quad * 4) = pk.u;
            }
        }
        __threadfence_block();   // P rows wave-private: drain + no-reorder suffices

        // ======== stage C': outacc += P^T x (U^T)^T ========
        #pragma unroll
        for (int kt = 0; kt < 2; ++kt) {
            union { bf16x8 v; u32 u[4]; } Af;
            #pragma unroll
            for (int q2 = 0; q2 < 4; ++q2)
                Af.u[q2] = *(const u32*)(pl + jc * PSTR + kt * 32 + quad * 8 + 2 * q2);
            #pragma unroll
            for (int nt = 0; nt < 8; ++nt) {
                const int rr = nt * 16 + lid;
                bf16x8 Bu = *(const bf16x8*)(us + rr * 64 + ((((kt * 32 + quad * 8) >> 3) ^ rr) & 7) * 8 + ((kt * 32 + quad * 8) & 7));
                outacc[nt] = __builtin_amdgcn_mfma_f32_16x16x32_bf16(Af.v, Bu, outacc[nt], 0, 0, 0);
            }
        }
        __syncthreads();   // before next head overwrites qs/ks/us
    }

    // ======== epilogue: out[n][dd][p(j)] = acc + bo[dd]  (fp32 output) ========
    float* outp = out + n * DDIM * PTOT;
    #pragma unroll
    for (int nt = 0; nt < 8; ++nt) {
        const int dd = nt * 16 + lid;
        const float bov = bo[dd];
        #pragma unroll
        for (int r = 0; r < 4; ++r) {
            const int jj = 16 * w + quad * 4 + r;
            if (jj < NTOK) {
                const int a = jj / 7, b = jj - a * 7;
                outp[dd * PTOT + pbase + a * CWID + b] = outacc[nt][r] + bov;
            }
        }
    }
}

extern "C" void kernel_launch(void* const* d_in, const int* in_sizes, int n_in,
                              void* d_out, int out_size, void* d_ws, size_t ws_size,
                              hipStream_t stream) {
    (void)in_sizes; (void)n_in; (void)ws_size; (void)out_size;
    prep<<<264, 256, 0, stream>>>((const float*)d_in[1], (const float*)d_in[3],
                                  (const float*)d_in[5], (const float*)d_in[7],
                                  (const float*)d_in[6], (u16*)d_ws);
    winattn<<<NBATCH * 256, 256, 0, stream>>>(
        (const float*)d_in[0], (const u16*)d_ws,
        (const float*)d_in[2], (const float*)d_in[4],
        (const float*)d_in[8], (const float*)d_in[9], (float*)d_out);
}

// Round 11
// 443.712 us; speedup vs baseline: 1.0394x; 1.0394x over previous
//
#include <hip/hip_runtime.h>

typedef unsigned short u16;
typedef unsigned int u32;
typedef __attribute__((ext_vector_type(8))) short bf16x8;   // 8 bf16 = 4 VGPRs
typedef __attribute__((ext_vector_type(4))) float f32x4;
typedef __attribute__((ext_vector_type(2))) unsigned int u32x2;

#define NBATCH 4
#define DDIM   128
#define NHEAD  8
#define PTOT   12544
#define CWID   112     // patch grid width
#define NTOK   49      // tokens per 7x7 window
#define PSTR   68      // p_lds row stride (u16 elems)

// LDS (u16 units). xw staging overlays ts/us (consumed into regs before head loop).
#define OFF_TS 0                    // 49*128 = 6272  T [i][d'] swz128
#define OFF_US 6272                 // 128*64 = 8192  U^T [dd][i] swz64
#define OFF_PL 14464                // 49*68  = 3332  P^T [j][i]
#define OFF_PC 17796                // 169*8  = 1352  pos bias bf16
#define OFF_MF 19148                // 1024 fp32 = 2048 u16  (M_h tables)
#define OFF_CS 21196                // 512 fp32 = 1024 u16   (c_i per head)
#define LDS_TOT 22220               // 44440 B

// ws layout: u16 Gt (8 x 128x128, transposed) | u16 Wc (8 x 128x128) | fp32 block
// fp32 block at u16 offset 262144: bcv[1024] | r[1024] | M[1024] | s[8]
#define WS_WC   131072
#define WS_F32  262144

__device__ __forceinline__ int swz128(int row, int col) {
    return row * 128 + ((((col >> 3) ^ row) & 15) << 3) + (col & 7);
}
__device__ __forceinline__ int swz64(int row, int col) {
    return row * 64 + ((((col >> 3) ^ row) & 7) << 3) + (col & 7);
}
__device__ __forceinline__ float bf2f(u16 u) {
    union { u32 i; float f; } x; x.i = ((u32)u) << 16; return x.f;
}
__device__ __forceinline__ u16 f2bf(float f) {
    union { float f; u32 u; } v; v.f = f;
    return (u16)((v.u + 0x7fffu + ((v.u >> 16) & 1u)) >> 16);
}

// ---- prepass (16 blocks): b<8 -> Wc_h = Wo_h*Wv_h + bcv; b in 8..15 -> Gt_h = (Wk_h^T Wq_h)^T + r/M/s ----
__global__ void __launch_bounds__(256) prep(
    const float* __restrict__ Wq, const float* __restrict__ Wk,
    const float* __restrict__ Wv, const float* __restrict__ Wo,
    const float* __restrict__ bq, const float* __restrict__ bk,
    const float* __restrict__ bv, u16* __restrict__ ws)
{
    __shared__ u16 lm[32768];
    const int tid = threadIdx.x;
    const int b = blockIdx.x;
    const bool isG = (b >= 8);
    const int h = b & 7;
    float* fb = (float*)(ws + WS_F32);

    if (!isG) {
        // lm[0): A = Wo_h [dd][dh]; lm[16384): B = Wv_h^T [d][dh]
        for (int idx = tid; idx < 16384; idx += 256) {
            const int dd = idx >> 7, dh = idx & 127;
            lm[swz128(dd, dh)] = f2bf(Wo[dd * 1024 + h * 128 + dh]);
        }
        for (int idx = tid; idx < 16384; idx += 256) {
            const int dh = idx >> 7, d = idx & 127;
            lm[16384 + swz128(d, dh)] = f2bf(Wv[(h * 128 + dh) * 128 + d]);
        }
        if (tid < 128) {
            float s = 0.f;
            for (int dh = 0; dh < 128; ++dh)
                s += Wo[tid * 1024 + h * 128 + dh] * bv[h * 128 + dh];
            fb[h * 128 + tid] = s;                 // bcv
        }
    } else {
        // lm[0): A = Wk_h^T [d][dh]; lm[16384): B = Wq_h as [d'][dh]
        for (int idx = tid; idx < 16384; idx += 256) {
            const int dh = idx >> 7, d = idx & 127;
            lm[swz128(d, dh)] = f2bf(Wk[(h * 128 + dh) * 128 + d]);
        }
        for (int idx = tid; idx < 16384; idx += 256) {
            const int dh = idx >> 7, dp = idx & 127;
            lm[16384 + swz128(dp, dh)] = f2bf(Wq[(h * 128 + dh) * 128 + dp]);
        }
        if (tid < 128) {
            float r = 0.f, m = 0.f;
            for (int dh = 0; dh < 128; ++dh) {
                r += bk[h * 128 + dh] * Wq[(h * 128 + dh) * 128 + tid];
                m += Wk[(h * 128 + dh) * 128 + tid] * bq[h * 128 + dh];
            }
            fb[1024 + h * 128 + tid] = r;          // r_h
            fb[2048 + h * 128 + tid] = m;          // M_h
        }
        if (tid == 0) {
            float s = 0.f;
            for (int dh = 0; dh < 128; ++dh) s += bk[h * 128 + dh] * bq[h * 128 + dh];
            fb[3072 + h] = s;                      // s_h
        }
    }
    __syncthreads();

    const int w = tid >> 6, lane = tid & 63, quad = lane >> 4, lid = lane & 15;
    const f32x4 z4 = {0.f, 0.f, 0.f, 0.f};
    u16* dst = ws + (isG ? 0 : WS_WC) + h * 16384;
    #pragma unroll
    for (int mtl = 0; mtl < 2; ++mtl) {
        const int mt = 2 * w + mtl;
        bf16x8 A[4];
        #pragma unroll
        for (int kt = 0; kt < 4; ++kt)
            A[kt] = *(const bf16x8*)(lm + swz128(mt * 16 + lid, kt * 32 + quad * 8));
        #pragma unroll
        for (int nt = 0; nt < 8; ++nt) {
            f32x4 acc = z4;
            #pragma unroll
            for (int kt = 0; kt < 4; ++kt) {
                bf16x8 B = *(const bf16x8*)(lm + 16384 + swz128(nt * 16 + lid, kt * 32 + quad * 8));
                acc = __builtin_amdgcn_mfma_f32_16x16x32_bf16(A[kt], B, acc, 0, 0, 0);
            }
            #pragma unroll
            for (int r = 0; r < 4; ++r) {
                const int row = mt * 16 + quad * 4 + r, col = nt * 16 + lid;
                if (isG) dst[col * 128 + row] = f2bf(acc[r]);   // store G transposed
                else     dst[row * 128 + col] = f2bf(acc[r]);   // Wc row-major
            }
        }
    }
}

// 256 threads = 4 waves; wave w owns query group j in [16w,16w+16).
// x-window fragments live in 64 VGPRs (loose VGPR budget: launch_bounds(256,2)).
__global__ void __launch_bounds__(256, 2)
winattn(const float* __restrict__ xg, const u16* __restrict__ ws,
        const float* __restrict__ bo, const float* __restrict__ posf,
        float* __restrict__ out)
{
    __shared__ u16 sm[LDS_TOT];
    u16* xw = sm;            // staging overlay on ts/us
    u16* ts = sm + OFF_TS;   // T [i][d'] swz128
    u16* us = sm + OFF_US;   // U^T [dd][i] swz64
    u16* pl = sm + OFF_PL;   // P^T [j][i], wave-private rows
    u16* pc = sm + OFF_PC;   // pos bias bf16
    float* Mf = (float*)(sm + OFF_MF);
    float* cs = (float*)(sm + OFF_CS);

    const int tid  = threadIdx.x;
    const int w    = tid >> 6;
    const int lane = tid & 63;
    const int quad = lane >> 4;
    const int lid  = lane & 15;
    const int bx   = blockIdx.x;
    const int n    = bx >> 8;
    const int win  = bx & 255;
    const int pbase = (win >> 4) * 7 * CWID + (win & 15) * 7;

    const bf16x8 zf = {0,0,0,0,0,0,0,0};
    const f32x4  z4 = {0.f,0.f,0.f,0.f};

    const u16* Gt  = ws;
    const u16* Wcw = ws + WS_WC;
    const float* fb  = (const float*)(ws + WS_F32);
    const float* bcv = fb;
    const float* rP  = fb + 1024;
    const float* MP  = fb + 2048;
    const float* sP  = fb + 3072;

    // ---- stage pos table + M tables + x window ----
    for (int i = tid; i < 169 * NHEAD; i += 256) pc[i] = f2bf(posf[i]);
    for (int i = tid; i < 1024; i += 256) Mf[i] = MP[i];
    const float* xn = xg + n * DDIM * PTOT;
    for (int idx = tid; idx < DDIM * NTOK; idx += 256) {
        int d = idx / NTOK;
        int t = idx - d * NTOK;
        int a = t / 7, b = t - a * 7;
        xw[swz128(t, d)] = f2bf(xn[d * PTOT + pbase + a * CWID + b]);
    }
    __syncthreads();

    // ---- hoist x fragments (A-layout == B-layout: lane lid = token, quad*8 = d) ----
    bf16x8 xfrag[4][4];
    #pragma unroll
    for (int mt = 0; mt < 4; ++mt)
        #pragma unroll
        for (int kt = 0; kt < 4; ++kt)
            xfrag[mt][kt] = (mt * 16 + lid < NTOK)
                ? *(const bf16x8*)(xw + swz128(mt * 16 + lid, kt * 32 + quad * 8)) : zf;

    // ---- c_i tables (exact bq/bk terms): cs[h][i] = x_i . M_h + s_h ----
    for (int hh = w; hh < NHEAD; hh += 4) {
        const float sh = sP[hh];
        #pragma unroll
        for (int mt = 0; mt < 4; ++mt) {
            float c = 0.f;
            #pragma unroll
            for (int kt = 0; kt < 4; ++kt)
                #pragma unroll
                for (int jj = 0; jj < 8; ++jj)
                    c += bf2f((u16)xfrag[mt][kt][jj]) * Mf[hh * 128 + kt * 32 + quad * 8 + jj];
            c += __shfl_xor(c, 16);
            c += __shfl_xor(c, 32);
            if (quad == 0) cs[hh * 64 + mt * 16 + lid] = c + sh;
        }
    }
    __syncthreads();   // xw dead (ts/us may overlay); cs visible

    f32x4 outacc[8];
    #pragma unroll
    for (int nt = 0; nt < 8; ++nt) outacc[nt] = z4;

    const int j = 16 * w + lid;
    const int jc = j < NTOK ? j : NTOK - 1;

    for (int h = 0; h < NHEAD; ++h) {
        // ======== stage A: T = X*G^T + r  and  U^T = Wc*X^T + bcv ========
        #pragma unroll
        for (int ntl = 0; ntl < 2; ++ntl) {
            const int nt = 2 * w + ntl;
            bf16x8 B[4];
            #pragma unroll
            for (int kt = 0; kt < 4; ++kt)
                B[kt] = *(const bf16x8*)(Gt + h * 16384 + (nt * 16 + lid) * 128 + kt * 32 + quad * 8);
            const float rbias = rP[h * 128 + nt * 16 + lid];
            #pragma unroll
            for (int mt = 0; mt < 4; ++mt) {
                f32x4 acc = z4;
                #pragma unroll
                for (int kt = 0; kt < 4; ++kt)
                    acc = __builtin_amdgcn_mfma_f32_16x16x32_bf16(xfrag[mt][kt], B[kt], acc, 0, 0, 0);
                #pragma unroll
                for (int r = 0; r < 4; ++r) {
                    const int t = mt * 16 + quad * 4 + r;
                    if (t < NTOK)
                        ts[swz128(t, nt * 16 + lid)] = f2bf(acc[r] + rbias);
                }
            }
        }
        #pragma unroll
        for (int mtl = 0; mtl < 2; ++mtl) {
            const int mt = 2 * w + mtl;
            bf16x8 A[4];
            #pragma unroll
            for (int kt = 0; kt < 4; ++kt)
                A[kt] = *(const bf16x8*)(Wcw + h * 16384 + (mt * 16 + lid) * 128 + kt * 32 + quad * 8);
            float bias[4];
            #pragma unroll
            for (int r = 0; r < 4; ++r)
                bias[r] = bcv[h * 128 + mt * 16 + quad * 4 + r];
            #pragma unroll
            for (int nt = 0; nt < 4; ++nt) {
                f32x4 acc = z4;
                #pragma unroll
                for (int kt = 0; kt < 4; ++kt)
                    acc = __builtin_amdgcn_mfma_f32_16x16x32_bf16(A[kt], xfrag[nt][kt], acc, 0, 0, 0);
                #pragma unroll
                for (int r = 0; r < 4; ++r)
                    us[swz64(mt * 16 + quad * 4 + r, nt * 16 + lid)] = f2bf(acc[r] + bias[r]);
            }
        }
        __syncthreads();

        // ======== stage B: S = T * X^T (+c_i), softmax, P write ========
        f32x4 S[4];
        #pragma unroll
        for (int mt = 0; mt < 4; ++mt) {
            S[mt] = z4;
            #pragma unroll
            for (int kt = 0; kt < 4; ++kt) {
                bf16x8 A = *(const bf16x8*)(ts + swz128(mt * 16 + lid, kt * 32 + quad * 8));
                S[mt] = __builtin_amdgcn_mfma_f32_16x16x32_bf16(A, xfrag[w][kt], S[mt], 0, 0, 0);
            }
        }
        const int aj = jc / 7, bj = jc - aj * 7;
        float sv[4][4];
        float mx = -3.0e38f;
        #pragma unroll
        for (int mt = 0; mt < 4; ++mt)
            #pragma unroll
            for (int r = 0; r < 4; ++r) {
                const int ii = mt * 16 + quad * 4 + r;
                float vvv;
                if (ii < NTOK) {
                    const int ai = ii / 7, bi = ii - ai * 7;
                    const int rel = (ai - aj + 6) + 13 * (bi - bj + 6);
                    vvv = (S[mt][r] + cs[h * 64 + ii]) * 0.08838834764831845f + bf2f(pc[rel * NHEAD + h]);
                } else {
                    vvv = -3.0e38f;
                }
                sv[mt][r] = vvv;
                mx = fmaxf(mx, vvv);
            }
        mx = fmaxf(mx, __shfl_xor(mx, 16));
        mx = fmaxf(mx, __shfl_xor(mx, 32));
        float ssum = 0.f;
        #pragma unroll
        for (int mt = 0; mt < 4; ++mt)
            #pragma unroll
            for (int r = 0; r < 4; ++r) {
                const float e = __expf(sv[mt][r] - mx);
                sv[mt][r] = e;
                ssum += e;
            }
        ssum += __shfl_xor(ssum, 16);
        ssum += __shfl_xor(ssum, 32);
        const float inv = 1.0f / ssum;
        if (j < NTOK) {
            #pragma unroll
            for (int mt = 0; mt < 4; ++mt) {
                union { u16 s[4]; u32x2 u; } pk;
                #pragma unroll
                for (int r = 0; r < 4; ++r) pk.s[r] = f2bf(sv[mt][r] * inv);
                *(u32x2*)(pl + j * PSTR + mt * 16 + quad * 4) = pk.u;
            }
        }
        __threadfence_block();   // P rows wave-private: drain + no-reorder suffices

        // ======== stage C': outacc += P^T x (U^T)^T ========
        #pragma unroll
        for (int kt = 0; kt < 2; ++kt) {
            union { bf16x8 v; u32 u[4]; } Af;
            #pragma unroll
            for (int q2 = 0; q2 < 4; ++q2)
                Af.u[q2] = *(const u32*)(pl + jc * PSTR + kt * 32 + quad * 8 + 2 * q2);
            #pragma unroll
            for (int nt = 0; nt < 8; ++nt) {
                bf16x8 Bu = *(const bf16x8*)(us + swz64(nt * 16 + lid, kt * 32 + quad * 8));
                outacc[nt] = __builtin_amdgcn_mfma_f32_16x16x32_bf16(Af.v, Bu, outacc[nt], 0, 0, 0);
            }
        }
        __syncthreads();   // before next head overwrites ts/us
    }

    // ======== epilogue: out[n][dd][p(j)] = acc + bo[dd]  (fp32 output) ========
    float* outp = out + n * DDIM * PTOT;
    #pragma unroll
    for (int nt = 0; nt < 8; ++nt) {
        const int dd = nt * 16 + lid;
        const float bov = bo[dd];
        #pragma unroll
        for (int r = 0; r < 4; ++r) {
            const int jj = 16 * w + quad * 4 + r;
            if (jj < NTOK) {
                const int a = jj / 7, b = jj - a * 7;
                outp[dd * PTOT + pbase + a * CWID + b] = outacc[nt][r] + bov;
            }
        }
    }
}

extern "C" void kernel_launch(void* const* d_in, const int* in_sizes, int n_in,
                              void* d_out, int out_size, void* d_ws, size_t ws_size,
                              hipStream_t stream) {
    (void)in_sizes; (void)n_in; (void)ws_size; (void)out_size;
    prep<<<16, 256, 0, stream>>>((const float*)d_in[1], (const float*)d_in[3],
                                 (const float*)d_in[5], (const float*)d_in[7],
                                 (const float*)d_in[2], (const float*)d_in[4],
                                 (const float*)d_in[6], (u16*)d_ws);
    winattn<<<NBATCH * 256, 256, 0, stream>>>(
        (const float*)d_in[0], (const u16*)d_ws,
        (const float*)d_in[8], (const float*)d_in[9], (float*)d_out);
}

// Round 12
// 258.967 us; speedup vs baseline: 1.7808x; 1.7134x over previous
//
#include <hip/hip_runtime.h>

typedef unsigned short u16;
typedef unsigned int u32;
typedef __attribute__((ext_vector_type(8))) short bf16x8;   // 8 bf16 = 4 VGPRs
typedef __attribute__((ext_vector_type(4))) float f32x4;
typedef __attribute__((ext_vector_type(2))) unsigned int u32x2;

#define NBATCH 4
#define DDIM   128
#define NHEAD  8
#define PTOT   12544
#define CWID   112     // patch grid width
#define NTOK   49      // tokens per 7x7 window
#define PSTR   68      // p_lds row stride (u16 elems)

// LDS (u16 units). xw staging overlays ts/us (consumed into regs before head loop).
#define OFF_TS 0                    // 49*128 = 6272  T [i][d'] swz128
#define OFF_US 6272                 // 128*64 = 8192  U^T [dd][i] swz64
#define OFF_PL 14464                // 49*68  = 3332  P^T [j][i]
#define OFF_PC 17796                // 169*8  = 1352  pos bias bf16
#define OFF_MF 19148                // 1024 fp32 = 2048 u16  (M_h tables)
#define OFF_CS 21196                // 512 fp32 = 1024 u16   (c_i per head)
#define LDS_TOT 22220               // 44440 B

// ws layout: u16 Gt (8 x 128x128, transposed) | u16 Wc (8 x 128x128) | fp32 block
// fp32 block at u16 offset 262144: bcv[1024] | r[1024] | M[1024] | s[8]
#define WS_WC   131072
#define WS_F32  262144

__device__ __forceinline__ int swz128(int row, int col) {
    return row * 128 + ((((col >> 3) ^ row) & 15) << 3) + (col & 7);
}
__device__ __forceinline__ int swz64(int row, int col) {
    return row * 64 + ((((col >> 3) ^ row) & 7) << 3) + (col & 7);
}
__device__ __forceinline__ float bf2f(u16 u) {
    union { u32 i; float f; } x; x.i = ((u32)u) << 16; return x.f;
}
__device__ __forceinline__ u16 f2bf(float f) {
    union { float f; u32 u; } v; v.f = f;
    return (u16)((v.u + 0x7fffu + ((v.u >> 16) & 1u)) >> 16);
}

// ---- prepass (16 blocks): b<8 -> Wc_h = Wo_h*Wv_h + bcv; b in 8..15 -> Gt_h = (Wk_h^T Wq_h)^T + r/M/s ----
__global__ void __launch_bounds__(256) prep(
    const float* __restrict__ Wq, const float* __restrict__ Wk,
    const float* __restrict__ Wv, const float* __restrict__ Wo,
    const float* __restrict__ bq, const float* __restrict__ bk,
    const float* __restrict__ bv, u16* __restrict__ ws)
{
    __shared__ u16 lm[32768];
    const int tid = threadIdx.x;
    const int b = blockIdx.x;
    const bool isG = (b >= 8);
    const int h = b & 7;
    float* fb = (float*)(ws + WS_F32);

    if (!isG) {
        // lm[0): A = Wo_h [dd][dh]; lm[16384): B = Wv_h^T [d][dh]
        for (int idx = tid; idx < 16384; idx += 256) {
            const int dd = idx >> 7, dh = idx & 127;
            lm[swz128(dd, dh)] = f2bf(Wo[dd * 1024 + h * 128 + dh]);
        }
        for (int idx = tid; idx < 16384; idx += 256) {
            const int dh = idx >> 7, d = idx & 127;
            lm[16384 + swz128(d, dh)] = f2bf(Wv[(h * 128 + dh) * 128 + d]);
        }
        if (tid < 128) {
            float s = 0.f;
            for (int dh = 0; dh < 128; ++dh)
                s += Wo[tid * 1024 + h * 128 + dh] * bv[h * 128 + dh];
            fb[h * 128 + tid] = s;                 // bcv
        }
    } else {
        // lm[0): A = Wk_h^T [d][dh]; lm[16384): B = Wq_h as [d'][dh]
        for (int idx = tid; idx < 16384; idx += 256) {
            const int dh = idx >> 7, d = idx & 127;
            lm[swz128(d, dh)] = f2bf(Wk[(h * 128 + dh) * 128 + d]);
        }
        for (int idx = tid; idx < 16384; idx += 256) {
            const int dh = idx >> 7, dp = idx & 127;
            lm[16384 + swz128(dp, dh)] = f2bf(Wq[(h * 128 + dh) * 128 + dp]);
        }
        if (tid < 128) {
            float r = 0.f, m = 0.f;
            for (int dh = 0; dh < 128; ++dh) {
                r += bk[h * 128 + dh] * Wq[(h * 128 + dh) * 128 + tid];
                m += Wk[(h * 128 + dh) * 128 + tid] * bq[h * 128 + dh];
            }
            fb[1024 + h * 128 + tid] = r;          // r_h
            fb[2048 + h * 128 + tid] = m;          // M_h
        }
        if (tid == 0) {
            float s = 0.f;
            for (int dh = 0; dh < 128; ++dh) s += bk[h * 128 + dh] * bq[h * 128 + dh];
            fb[3072 + h] = s;                      // s_h
        }
    }
    __syncthreads();

    const int w = tid >> 6, lane = tid & 63, quad = lane >> 4, lid = lane & 15;
    const f32x4 z4 = {0.f, 0.f, 0.f, 0.f};
    u16* dst = ws + (isG ? 0 : WS_WC) + h * 16384;
    #pragma unroll
    for (int mtl = 0; mtl < 2; ++mtl) {
        const int mt = 2 * w + mtl;
        bf16x8 A[4];
        #pragma unroll
        for (int kt = 0; kt < 4; ++kt)
            A[kt] = *(const bf16x8*)(lm + swz128(mt * 16 + lid, kt * 32 + quad * 8));
        #pragma unroll
        for (int nt = 0; nt < 8; ++nt) {
            f32x4 acc = z4;
            #pragma unroll
            for (int kt = 0; kt < 4; ++kt) {
                bf16x8 B = *(const bf16x8*)(lm + 16384 + swz128(nt * 16 + lid, kt * 32 + quad * 8));
                acc = __builtin_amdgcn_mfma_f32_16x16x32_bf16(A[kt], B, acc, 0, 0, 0);
            }
            #pragma unroll
            for (int r = 0; r < 4; ++r) {
                const int row = mt * 16 + quad * 4 + r, col = nt * 16 + lid;
                if (isG) dst[col * 128 + row] = f2bf(acc[r]);   // store G transposed
                else     dst[row * 128 + col] = f2bf(acc[r]);   // Wc row-major
            }
        }
    }
}

// 256 threads = 4 waves; wave w owns query group j in [16w,16w+16).
// x-window fragments live in 64+16 VGPRs; ALL register-array indices are
// compile-time (dynamic indexing demotes arrays to scratch -> r11's 300MB spill).
__global__ void __launch_bounds__(256, 2)
winattn(const float* __restrict__ xg, const u16* __restrict__ ws,
        const float* __restrict__ bo, const float* __restrict__ posf,
        float* __restrict__ out)
{
    __shared__ u16 sm[LDS_TOT];
    u16* xw = sm;            // staging overlay on ts/us
    u16* ts = sm + OFF_TS;   // T [i][d'] swz128
    u16* us = sm + OFF_US;   // U^T [dd][i] swz64
    u16* pl = sm + OFF_PL;   // P^T [j][i], wave-private rows
    u16* pc = sm + OFF_PC;   // pos bias bf16
    float* Mf = (float*)(sm + OFF_MF);
    float* cs = (float*)(sm + OFF_CS);

    const int tid  = threadIdx.x;
    const int w    = tid >> 6;
    const int lane = tid & 63;
    const int quad = lane >> 4;
    const int lid  = lane & 15;
    const int bx   = blockIdx.x;
    const int n    = bx >> 8;
    const int win  = bx & 255;
    const int pbase = (win >> 4) * 7 * CWID + (win & 15) * 7;

    const bf16x8 zf = {0,0,0,0,0,0,0,0};
    const f32x4  z4 = {0.f,0.f,0.f,0.f};

    const u16* Gt  = ws;
    const u16* Wcw = ws + WS_WC;
    const float* fb  = (const float*)(ws + WS_F32);
    const float* bcv = fb;
    const float* rP  = fb + 1024;
    const float* MP  = fb + 2048;
    const float* sP  = fb + 3072;

    // ---- stage pos table + M tables + x window ----
    for (int i = tid; i < 169 * NHEAD; i += 256) pc[i] = f2bf(posf[i]);
    for (int i = tid; i < 1024; i += 256) Mf[i] = MP[i];
    const float* xn = xg + n * DDIM * PTOT;
    for (int idx = tid; idx < DDIM * NTOK; idx += 256) {
        int d = idx / NTOK;
        int t = idx - d * NTOK;
        int a = t / 7, b = t - a * 7;
        xw[swz128(t, d)] = f2bf(xn[d * PTOT + pbase + a * CWID + b]);
    }
    __syncthreads();

    // ---- hoist x fragments (A-layout == B-layout: lane lid = token, quad*8 = d) ----
    bf16x8 xfrag[4][4];
    #pragma unroll
    for (int mt = 0; mt < 4; ++mt)
        #pragma unroll
        for (int kt = 0; kt < 4; ++kt)
            xfrag[mt][kt] = (mt * 16 + lid < NTOK)
                ? *(const bf16x8*)(xw + swz128(mt * 16 + lid, kt * 32 + quad * 8)) : zf;
    // xq: this wave's own query-row fragment (stage-B B-operand) — direct LDS
    // load at constant indices, NOT xfrag[w][.] (dynamic reg index = scratch!)
    const int j = 16 * w + lid;
    bf16x8 xq[4];
    #pragma unroll
    for (int kt = 0; kt < 4; ++kt)
        xq[kt] = (j < NTOK)
            ? *(const bf16x8*)(xw + swz128(j, kt * 32 + quad * 8)) : zf;

    // ---- c_i tables (exact bq/bk terms): cs[h][i] = x_i . M_h + s_h ----
    for (int hh = w; hh < NHEAD; hh += 4) {
        const float sh = sP[hh];
        #pragma unroll
        for (int mt = 0; mt < 4; ++mt) {
            float c = 0.f;
            #pragma unroll
            for (int kt = 0; kt < 4; ++kt)
                #pragma unroll
                for (int jj = 0; jj < 8; ++jj)
                    c += bf2f((u16)xfrag[mt][kt][jj]) * Mf[hh * 128 + kt * 32 + quad * 8 + jj];
            c += __shfl_xor(c, 16);
            c += __shfl_xor(c, 32);
            if (quad == 0) cs[hh * 64 + mt * 16 + lid] = c + sh;
        }
    }
    __syncthreads();   // xw dead (ts/us may overlay); cs visible

    f32x4 outacc[8];
    #pragma unroll
    for (int nt = 0; nt < 8; ++nt) outacc[nt] = z4;

    const int jc = j < NTOK ? j : NTOK - 1;

    for (int h = 0; h < NHEAD; ++h) {
        // ======== stage A: T = X*G^T + r  and  U^T = Wc*X^T + bcv ========
        #pragma unroll
        for (int ntl = 0; ntl < 2; ++ntl) {
            const int nt = 2 * w + ntl;
            bf16x8 B[4];
            #pragma unroll
            for (int kt = 0; kt < 4; ++kt)
                B[kt] = *(const bf16x8*)(Gt + h * 16384 + (nt * 16 + lid) * 128 + kt * 32 + quad * 8);
            const float rbias = rP[h * 128 + nt * 16 + lid];
            #pragma unroll
            for (int mt = 0; mt < 4; ++mt) {
                f32x4 acc = z4;
                #pragma unroll
                for (int kt = 0; kt < 4; ++kt)
                    acc = __builtin_amdgcn_mfma_f32_16x16x32_bf16(xfrag[mt][kt], B[kt], acc, 0, 0, 0);
                #pragma unroll
                for (int r = 0; r < 4; ++r) {
                    const int t = mt * 16 + quad * 4 + r;
                    if (t < NTOK)
                        ts[swz128(t, nt * 16 + lid)] = f2bf(acc[r] + rbias);
                }
            }
        }
        #pragma unroll
        for (int mtl = 0; mtl < 2; ++mtl) {
            const int mt = 2 * w + mtl;
            bf16x8 A[4];
            #pragma unroll
            for (int kt = 0; kt < 4; ++kt)
                A[kt] = *(const bf16x8*)(Wcw + h * 16384 + (mt * 16 + lid) * 128 + kt * 32 + quad * 8);
            float bias[4];
            #pragma unroll
            for (int r = 0; r < 4; ++r)
                bias[r] = bcv[h * 128 + mt * 16 + quad * 4 + r];
            #pragma unroll
            for (int nt = 0; nt < 4; ++nt) {
                f32x4 acc = z4;
                #pragma unroll
                for (int kt = 0; kt < 4; ++kt)
                    acc = __builtin_amdgcn_mfma_f32_16x16x32_bf16(A[kt], xfrag[nt][kt], acc, 0, 0, 0);
                #pragma unroll
                for (int r = 0; r < 4; ++r)
                    us[swz64(mt * 16 + quad * 4 + r, nt * 16 + lid)] = f2bf(acc[r] + bias[r]);
            }
        }
        __syncthreads();

        // ======== stage B: S = T * X^T (+c_i), softmax, P write ========
        f32x4 S[4];
        #pragma unroll
        for (int mt = 0; mt < 4; ++mt) {
            S[mt] = z4;
            #pragma unroll
            for (int kt = 0; kt < 4; ++kt) {
                bf16x8 A = *(const bf16x8*)(ts + swz128(mt * 16 + lid, kt * 32 + quad * 8));
                S[mt] = __builtin_amdgcn_mfma_f32_16x16x32_bf16(A, xq[kt], S[mt], 0, 0, 0);
            }
        }
        const int aj = jc / 7, bj = jc - aj * 7;
        float sv[4][4];
        float mx = -3.0e38f;
        #pragma unroll
        for (int mt = 0; mt < 4; ++mt)
            #pragma unroll
            for (int r = 0; r < 4; ++r) {
                const int ii = mt * 16 + quad * 4 + r;
                float vvv;
                if (ii < NTOK) {
                    const int ai = ii / 7, bi = ii - ai * 7;
                    const int rel = (ai - aj + 6) + 13 * (bi - bj + 6);
                    vvv = (S[mt][r] + cs[h * 64 + ii]) * 0.08838834764831845f + bf2f(pc[rel * NHEAD + h]);
                } else {
                    vvv = -3.0e38f;
                }
                sv[mt][r] = vvv;
                mx = fmaxf(mx, vvv);
            }
        mx = fmaxf(mx, __shfl_xor(mx, 16));
        mx = fmaxf(mx, __shfl_xor(mx, 32));
        float ssum = 0.f;
        #pragma unroll
        for (int mt = 0; mt < 4; ++mt)
            #pragma unroll
            for (int r = 0; r < 4; ++r) {
                const float e = __expf(sv[mt][r] - mx);
                sv[mt][r] = e;
                ssum += e;
            }
        ssum += __shfl_xor(ssum, 16);
        ssum += __shfl_xor(ssum, 32);
        const float inv = 1.0f / ssum;
        if (j < NTOK) {
            #pragma unroll
            for (int mt = 0; mt < 4; ++mt) {
                union { u16 s[4]; u32x2 u; } pk;
                #pragma unroll
                for (int r = 0; r < 4; ++r) pk.s[r] = f2bf(sv[mt][r] * inv);
                *(u32x2*)(pl + j * PSTR + mt * 16 + quad * 4) = pk.u;
            }
        }
        __threadfence_block();   // P rows wave-private: drain + no-reorder suffices

        // ======== stage C': outacc += P^T x (U^T)^T ========
        #pragma unroll
        for (int kt = 0; kt < 2; ++kt) {
            union { bf16x8 v; u32 u[4]; } Af;
            #pragma unroll
            for (int q2 = 0; q2 < 4; ++q2)
                Af.u[q2] = *(const u32*)(pl + jc * PSTR + kt * 32 + quad * 8 + 2 * q2);
            #pragma unroll
            for (int nt = 0; nt < 8; ++nt) {
                bf16x8 Bu = *(const bf16x8*)(us + swz64(nt * 16 + lid, kt * 32 + quad * 8));
                outacc[nt] = __builtin_amdgcn_mfma_f32_16x16x32_bf16(Af.v, Bu, outacc[nt], 0, 0, 0);
            }
        }
        __syncthreads();   // before next head overwrites ts/us
    }

    // ======== epilogue: out[n][dd][p(j)] = acc + bo[dd]  (fp32 output) ========
    float* outp = out + n * DDIM * PTOT;
    #pragma unroll
    for (int nt = 0; nt < 8; ++nt) {
        const int dd = nt * 16 + lid;
        const float bov = bo[dd];
        #pragma unroll
        for (int r = 0; r < 4; ++r) {
            const int jj = 16 * w + quad * 4 + r;
            if (jj < NTOK) {
                const int a = jj / 7, b = jj - a * 7;
                outp[dd * PTOT + pbase + a * CWID + b] = outacc[nt][r] + bov;
            }
        }
    }
}

extern "C" void kernel_launch(void* const* d_in, const int* in_sizes, int n_in,
                              void* d_out, int out_size, void* d_ws, size_t ws_size,
                              hipStream_t stream) {
    (void)in_sizes; (void)n_in; (void)ws_size; (void)out_size;
    prep<<<16, 256, 0, stream>>>((const float*)d_in[1], (const float*)d_in[3],
                                 (const float*)d_in[5], (const float*)d_in[7],
                                 (const float*)d_in[2], (const float*)d_in[4],
                                 (const float*)d_in[6], (u16*)d_ws);
    winattn<<<NBATCH * 256, 256, 0, stream>>>(
        (const float*)d_in[0], (const u16*)d_ws,
        (const float*)d_in[8], (const float*)d_in[9], (float*)d_out);
}

// Round 13
// 235.978 us; speedup vs baseline: 1.9543x; 1.0974x over previous
//
#include <hip/hip_runtime.h>
#include <hip/hip_bf16.h>

typedef unsigned short u16;
typedef unsigned int u32;
typedef __attribute__((ext_vector_type(8))) short bf16x8;   // 8 bf16 = 4 VGPRs
typedef __attribute__((ext_vector_type(4))) float f32x4;
typedef __attribute__((ext_vector_type(2))) unsigned int u32x2;

#define NBATCH 4
#define DDIM   128
#define NHEAD  8
#define PTOT   12544
#define CWID   112     // patch grid width
#define NTOK   49      // tokens per 7x7 window
#define PSTR   68      // p_lds row stride (u16 elems)
#define SCALE  0.08838834764831845f

// LDS (u16 units): double-buffered ts/us, then pl/pcf/Mf/cs
#define BUFSZ   14464               // ts 49..64*128=6272? ts uses 64*128=8192? see note: ts rows i<64 used: 64*128=8192! -> adjust
// NOTE: ts is indexed by i (token) rows 0..63 -> needs 64*128 = 8192, us 128*64 = 8192.
#undef BUFSZ
#define BUFSZ   16384               // ts 8192 + us 8192
#define OFF_US  8192
#define OFF_PL  32768               // 49*68 = 3332
#define OFF_PCF 36100               // 1352 f32 = 2704 u16
#define OFF_MF  38804               // 1024 f32 = 2048 u16
#define OFF_CS  40852               // 512 f32 = 1024 u16
#define LDS_TOT 41876               // 83752 B -> 2 blocks/CU (2x83752 = 167504 > 163840!!) -> trim

// 83.7KB x2 exceeds 160KB -> drop to single pl + shrink: use ts rows only 0..63 (needed),
// us 128x64 needed. Trim by removing Mf from LDS (read MP from global in cs build).
#undef OFF_MF
#undef OFF_CS
#undef LDS_TOT
#define OFF_CS  38804               // 512 f32 = 1024 u16
#define LDS_TOT 39828               // 79656 B -> 2 x 79656 = 159312 <= 163840 OK

__device__ __forceinline__ float bf2f(u16 u) {
    union { u32 i; float f; } x; x.i = ((u32)u) << 16; return x.f;
}
__device__ __forceinline__ u16 f2bf(float f) {
    union { float f; u32 u; } v; v.f = f;
    return (u16)((v.u + 0x7fffu + ((v.u >> 16) & 1u)) >> 16);
}
__device__ __forceinline__ u32 pk2(float a, float b) {
    union { __hip_bfloat162 h; u32 u; } c;
    float2 t; t.x = a; t.y = b;
    c.h = __float22bfloat162_rn(t);
    return c.u;
}
__device__ __forceinline__ int swz128(int row, int col) {
    return row * 128 + ((((col >> 3) ^ (row & 15)) & 15) << 3) + (col & 7);
}

// ws layout: u16 Gt (8 x 128x128, row-major d' rows, pre-scaled) | u16 Wc (8 x 128x128) | fp32 block
// fp32 block at u16 offset 262144: bcv[1024] | r[1024] (scaled) | M[1024] (scaled) | s[8] (scaled)
#define WS_WC   131072
#define WS_F32  262144

// ---- prepass (16 blocks): b<8 -> Wc_h = Wo_h*Wv_h + bcv; b>=8 -> Gt_h = scaled (Wk^T Wq)^T + r/M/s ----
__global__ void __launch_bounds__(256) prep(
    const float* __restrict__ Wq, const float* __restrict__ Wk,
    const float* __restrict__ Wv, const float* __restrict__ Wo,
    const float* __restrict__ bq, const float* __restrict__ bk,
    const float* __restrict__ bv, u16* __restrict__ ws)
{
    __shared__ u16 lm[32768];
    const int tid = threadIdx.x;
    const int b = blockIdx.x;
    const bool isG = (b >= 8);
    const int h = b & 7;
    float* fb = (float*)(ws + WS_F32);

    if (!isG) {
        for (int idx = tid; idx < 16384; idx += 256) {
            const int dd = idx >> 7, dh = idx & 127;
            lm[swz128(dd, dh)] = f2bf(Wo[dd * 1024 + h * 128 + dh]);
        }
        for (int idx = tid; idx < 16384; idx += 256) {
            const int dh = idx >> 7, d = idx & 127;
            lm[16384 + swz128(d, dh)] = f2bf(Wv[(h * 128 + dh) * 128 + d]);
        }
        if (tid < 128) {
            float s = 0.f;
            for (int dh = 0; dh < 128; ++dh)
                s += Wo[tid * 1024 + h * 128 + dh] * bv[h * 128 + dh];
            fb[h * 128 + tid] = s;                 // bcv (unscaled)
        }
    } else {
        for (int idx = tid; idx < 16384; idx += 256) {
            const int dh = idx >> 7, d = idx & 127;
            lm[swz128(d, dh)] = f2bf(Wk[(h * 128 + dh) * 128 + d]);
        }
        for (int idx = tid; idx < 16384; idx += 256) {
            const int dh = idx >> 7, dp = idx & 127;
            lm[16384 + swz128(dp, dh)] = f2bf(Wq[(h * 128 + dh) * 128 + dp]);
        }
        if (tid < 128) {
            float r = 0.f, m = 0.f;
            for (int dh = 0; dh < 128; ++dh) {
                r += bk[h * 128 + dh] * Wq[(h * 128 + dh) * 128 + tid];
                m += Wk[(h * 128 + dh) * 128 + tid] * bq[h * 128 + dh];
            }
            fb[1024 + h * 128 + tid] = r * SCALE;  // r_h scaled
            fb[2048 + h * 128 + tid] = m * SCALE;  // M_h scaled
        }
        if (tid == 0) {
            float s = 0.f;
            for (int dh = 0; dh < 128; ++dh) s += bk[h * 128 + dh] * bq[h * 128 + dh];
            fb[3072 + h] = s * SCALE;              // s_h scaled
        }
    }
    __syncthreads();

    const int w = tid >> 6, lane = tid & 63, quad = lane >> 4, lid = lane & 15;
    const f32x4 z4 = {0.f, 0.f, 0.f, 0.f};
    u16* dst = ws + (isG ? 0 : WS_WC) + h * 16384;
    const float gs = isG ? SCALE : 1.0f;
    #pragma unroll
    for (int mtl = 0; mtl < 2; ++mtl) {
        const int mt = 2 * w + mtl;
        bf16x8 A[4];
        #pragma unroll
        for (int kt = 0; kt < 4; ++kt)
            A[kt] = *(const bf16x8*)(lm + swz128(mt * 16 + lid, kt * 32 + quad * 8));
        #pragma unroll
        for (int nt = 0; nt < 8; ++nt) {
            f32x4 acc = z4;
            #pragma unroll
            for (int kt = 0; kt < 4; ++kt) {
                bf16x8 B = *(const bf16x8*)(lm + 16384 + swz128(nt * 16 + lid, kt * 32 + quad * 8));
                acc = __builtin_amdgcn_mfma_f32_16x16x32_bf16(A[kt], B, acc, 0, 0, 0);
            }
            #pragma unroll
            for (int r = 0; r < 4; ++r) {
                const int row = mt * 16 + quad * 4 + r, col = nt * 16 + lid;
                if (isG) dst[col * 128 + row] = f2bf(acc[r] * gs);   // Gt[d'][d] row-major
                else     dst[row * 128 + col] = f2bf(acc[r]);        // Wc[dd][d] row-major
            }
        }
    }
}

// 256 threads = 4 waves; wave w owns query group j in [16w,16w+16).
// Transposed stage-A GEMMs -> packed 8B LDS stores; double-buffered ts/us ->
// 1 barrier + 1 fence per head. All register-array indices compile-time.
__global__ void __launch_bounds__(256, 2)
winattn(const float* __restrict__ xg, const u16* __restrict__ ws,
        const float* __restrict__ bo, const float* __restrict__ posf,
        float* __restrict__ out)
{
    __shared__ __align__(16) u16 sm[LDS_TOT];
    u16* xw  = sm;                       // staging overlay on buf0 ts
    u16* pl  = sm + OFF_PL;              // P^T [j][i], wave-private rows
    float* pcf = (float*)(sm + OFF_PCF); // pos bias fp32
    float* cs  = (float*)(sm + OFF_CS);  // c_i per head

    const int tid  = threadIdx.x;
    const int w    = tid >> 6;
    const int lane = tid & 63;
    const int quad = lane >> 4;
    const int lid  = lane & 15;
    const int bx   = blockIdx.x;
    const int n    = bx >> 8;
    const int win  = bx & 255;
    const int pbase = (win >> 4) * 7 * CWID + (win & 15) * 7;

    const bf16x8 zf = {0,0,0,0,0,0,0,0};
    const f32x4  z4 = {0.f,0.f,0.f,0.f};

    const u16* Gt  = ws;
    const u16* Wcw = ws + WS_WC;
    const float* fb  = (const float*)(ws + WS_F32);
    const float* bcv = fb;
    const float* rP  = fb + 1024;
    const float* MP  = fb + 2048;
    const float* sP  = fb + 3072;

    // ---- stage pos table + x window ----
    for (int i = tid; i < 169 * NHEAD; i += 256) pcf[i] = posf[i];
    const float* xn = xg + n * DDIM * PTOT;
    for (int idx = tid; idx < DDIM * NTOK; idx += 256) {
        int d = idx / NTOK;
        int t = idx - d * NTOK;
        int a = t / 7, b = t - a * 7;
        xw[swz128(t, d)] = f2bf(xn[d * PTOT + pbase + a * CWID + b]);
    }
    __syncthreads();

    // ---- hoist x fragments (A-layout == B-layout: lane lid = token, quad*8 = d) ----
    bf16x8 xfrag[4][4];
    #pragma unroll
    for (int mt = 0; mt < 4; ++mt)
        #pragma unroll
        for (int kt = 0; kt < 4; ++kt)
            xfrag[mt][kt] = (mt * 16 + lid < NTOK)
                ? *(const bf16x8*)(xw + swz128(mt * 16 + lid, kt * 32 + quad * 8)) : zf;
    const int j = 16 * w + lid;
    bf16x8 xq[4];
    #pragma unroll
    for (int kt = 0; kt < 4; ++kt)
        xq[kt] = (j < NTOK)
            ? *(const bf16x8*)(xw + swz128(j, kt * 32 + quad * 8)) : zf;

    // ---- c_i tables (scaled): cs[h][i] = x_i . M_h + s_h  (MP from global/L2) ----
    for (int hh = w; hh < NHEAD; hh += 4) {
        const float sh = sP[hh];
        #pragma unroll
        for (int mt = 0; mt < 4; ++mt) {
            float c = 0.f;
            #pragma unroll
            for (int kt = 0; kt < 4; ++kt)
                #pragma unroll
                for (int jj = 0; jj < 8; ++jj)
                    c += bf2f((u16)xfrag[mt][kt][jj]) * MP[hh * 128 + kt * 32 + quad * 8 + jj];
            c += __shfl_xor(c, 16);
            c += __shfl_xor(c, 32);
            if (quad == 0) cs[hh * 64 + mt * 16 + lid] = c + sh;
        }
    }
    __syncthreads();   // xw dead (buffers may overlay); cs visible

    f32x4 outacc[8];
    #pragma unroll
    for (int nt = 0; nt < 8; ++nt) outacc[nt] = z4;

    const int jc = j < NTOK ? j : NTOK - 1;

    for (int h = 0; h < NHEAD; ++h) {
        u16* tsb = sm + (h & 1) * BUFSZ;            // T^T stored as ts[i][d'] swz128
        u16* usb = tsb + OFF_US;                    // U stored as us[dd][i] swz64-style

        // ======== stage A: T^T = G_h x X^T (+r)  — packed 8B stores ========
        #pragma unroll
        for (int mtl = 0; mtl < 2; ++mtl) {
            const int mt = 2 * w + mtl;             // d'-tile
            bf16x8 A[4];
            #pragma unroll
            for (int kt = 0; kt < 4; ++kt)
                A[kt] = *(const bf16x8*)(Gt + h * 16384 + (mt * 16 + lid) * 128 + kt * 32 + quad * 8);
            const f32x4 rb = *(const f32x4*)(rP + h * 128 + mt * 16 + quad * 4);
            const int dpb = mt * 16 + quad * 4;     // d' base for this lane's 4 outputs
            #pragma unroll
            for (int nt = 0; nt < 4; ++nt) {        // i-tiles
                f32x4 acc = z4;
                #pragma unroll
                for (int kt = 0; kt < 4; ++kt)
                    acc = __builtin_amdgcn_mfma_f32_16x16x32_bf16(A[kt], xfrag[nt][kt], acc, 0, 0, 0);
                const int i = nt * 16 + lid;
                u32x2 pkv;
                pkv.x = pk2(acc[0] + rb[0], acc[1] + rb[1]);
                pkv.y = pk2(acc[2] + rb[2], acc[3] + rb[3]);
                *(u32x2*)(tsb + i * 128 + ((((dpb >> 3) ^ (i & 15)) & 15) << 3) + (dpb & 7)) = pkv;
            }
        }
        // ======== stage A: U = X x Wc_h^T (+bcv) — packed 8B stores ========
        #pragma unroll
        for (int ntl = 0; ntl < 2; ++ntl) {
            const int nt = 2 * w + ntl;             // dd-tile
            bf16x8 B[4];
            #pragma unroll
            for (int kt = 0; kt < 4; ++kt)
                B[kt] = *(const bf16x8*)(Wcw + h * 16384 + (nt * 16 + lid) * 128 + kt * 32 + quad * 8);
            const int dd = nt * 16 + lid;
            const float bb = bcv[h * 128 + dd];
            #pragma unroll
            for (int mt = 0; mt < 4; ++mt) {        // i-tiles
                f32x4 acc = z4;
                #pragma unroll
                for (int kt = 0; kt < 4; ++kt)
                    acc = __builtin_amdgcn_mfma_f32_16x16x32_bf16(xfrag[mt][kt], B[kt], acc, 0, 0, 0);
                const int ib = mt * 16 + quad * 4;  // i base
                u32x2 pkv;
                pkv.x = pk2(acc[0] + bb, acc[1] + bb);
                pkv.y = pk2(acc[2] + bb, acc[3] + bb);
                *(u32x2*)(usb + dd * 64 + ((((ib >> 3) ^ (dd & 7)) & 7) << 3) + (ib & 7)) = pkv;
            }
        }
        __syncthreads();   // the ONLY block barrier per head

        // ======== stage B: S = T x X_j^T (+cs+pos), softmax, P write ========
        f32x4 S[4];
        #pragma unroll
        for (int mt = 0; mt < 4; ++mt) {
            S[mt] = z4;
            #pragma unroll
            for (int kt = 0; kt < 4; ++kt) {
                bf16x8 A = *(const bf16x8*)(tsb + (mt * 16 + lid) * 128 + ((((kt * 4 + quad) ^ lid) & 15) << 3));
                S[mt] = __builtin_amdgcn_mfma_f32_16x16x32_bf16(A, xq[kt], S[mt], 0, 0, 0);
            }
        }
        const int aj = jc / 7, bj = jc - aj * 7;
        float sv[4][4];
        float mx = -3.0e38f;
        #pragma unroll
        for (int mt = 0; mt < 4; ++mt)
            #pragma unroll
            for (int r = 0; r < 4; ++r) {
                const int ii = mt * 16 + quad * 4 + r;
                float vvv;
                if (ii < NTOK) {
                    const int ai = ii / 7, bi = ii - ai * 7;
                    const int rel = (ai - aj + 6) + 13 * (bi - bj + 6);
                    vvv = S[mt][r] + cs[h * 64 + ii] + pcf[rel * NHEAD + h];
                } else {
                    vvv = -3.0e38f;
                }
                sv[mt][r] = vvv;
                mx = fmaxf(mx, vvv);
            }
        mx = fmaxf(mx, __shfl_xor(mx, 16));
        mx = fmaxf(mx, __shfl_xor(mx, 32));
        float ssum = 0.f;
        #pragma unroll
        for (int mt = 0; mt < 4; ++mt)
            #pragma unroll
            for (int r = 0; r < 4; ++r) {
                const float e = __expf(sv[mt][r] - mx);
                sv[mt][r] = e;
                ssum += e;
            }
        ssum += __shfl_xor(ssum, 16);
        ssum += __shfl_xor(ssum, 32);
        const float inv = 1.0f / ssum;
        if (j < NTOK) {
            #pragma unroll
            for (int mt = 0; mt < 4; ++mt) {
                u32x2 pkv;
                pkv.x = pk2(sv[mt][0] * inv, sv[mt][1] * inv);
                pkv.y = pk2(sv[mt][2] * inv, sv[mt][3] * inv);
                *(u32x2*)(pl + j * PSTR + mt * 16 + quad * 4) = pkv;
            }
        }
        __threadfence_block();   // P rows wave-private: drain + no-reorder suffices

        // ======== stage C: outacc += P^T x U ========
        #pragma unroll
        for (int kt = 0; kt < 2; ++kt) {
            union { bf16x8 v; u32 u[4]; } Af;
            #pragma unroll
            for (int q2 = 0; q2 < 4; ++q2)
                Af.u[q2] = *(const u32*)(pl + jc * PSTR + kt * 32 + quad * 8 + 2 * q2);
            #pragma unroll
            for (int nt = 0; nt < 8; ++nt) {
                const int dd = nt * 16 + lid;
                bf16x8 Bu = *(const bf16x8*)(usb + dd * 64 + ((((kt * 4 + quad) ^ (dd & 7)) & 7) << 3));
                outacc[nt] = __builtin_amdgcn_mfma_f32_16x16x32_bf16(Af.v, Bu, outacc[nt], 0, 0, 0);
            }
        }
        // no end-of-head barrier: next head writes the OTHER ts/us buffer
    }

    // ======== epilogue: out[n][dd][p(j)] = acc + bo[dd]  (fp32 output) ========
    float* outp = out + n * DDIM * PTOT;
    #pragma unroll
    for (int nt = 0; nt < 8; ++nt) {
        const int dd = nt * 16 + lid;
        const float bov = bo[dd];
        #pragma unroll
        for (int r = 0; r < 4; ++r) {
            const int jj = 16 * w + quad * 4 + r;
            if (jj < NTOK) {
                const int a = jj / 7, b = jj - a * 7;
                outp[dd * PTOT + pbase + a * CWID + b] = outacc[nt][r] + bov;
            }
        }
    }
}

extern "C" void kernel_launch(void* const* d_in, const int* in_sizes, int n_in,
                              void* d_out, int out_size, void* d_ws, size_t ws_size,
                              hipStream_t stream) {
    (void)in_sizes; (void)n_in; (void)ws_size; (void)out_size;
    prep<<<16, 256, 0, stream>>>((const float*)d_in[1], (const float*)d_in[3],
                                 (const float*)d_in[5], (const float*)d_in[7],
                                 (const float*)d_in[2], (const float*)d_in[4],
                                 (const float*)d_in[6], (u16*)d_ws);
    winattn<<<NBATCH * 256, 256, 0, stream>>>(
        (const float*)d_in[0], (const u16*)d_ws,
        (const float*)d_in[8], (const float*)d_in[9], (float*)d_out);
}